// Round 12
// baseline (313.823 us; speedup 1.0000x reference)
//
#include <hip/hip_runtime.h>
#include <math.h>

#define HEADS 4
#define CH 64
#define HC 256   // HEADS*CH

typedef __attribute__((ext_vector_type(8))) short bf16x8;
typedef __attribute__((ext_vector_type(4))) float f32x4;

__device__ __forceinline__ float lrelu(float v) { return v > 0.f ? v : 0.2f * v; }

// fp32 -> bf16 bits, round-to-nearest-even
__device__ __forceinline__ unsigned int f2bf(float f) {
    unsigned int u = __float_as_uint(f);
    u += 0x7fffu + ((u >> 16) & 1u);
    return u >> 16;
}
__device__ __forceinline__ float bf2f(unsigned short u) {
    return __uint_as_float(((unsigned int)u) << 16);
}

__device__ __forceinline__ float4 wave_sum4(float4 v) {
#pragma unroll
    for (int m = 32; m; m >>= 1) {
        v.x += __shfl_xor(v.x, m);
        v.y += __shfl_xor(v.y, m);
        v.z += __shfl_xor(v.z, m);
        v.w += __shfl_xor(v.w, m);
    }
    return v;
}

// ---------------------------------------------------------------------------
// CSR build. count is XCD-affine and RECORDS each edge's slot (atomicAdd
// return) so scatter needs no atomics and no replication.
__global__ void count_kernel(const int* __restrict__ dst, int E, int vec_ok,
                             float scale8, int* __restrict__ deg,
                             int* __restrict__ slot) {
    int r = blockIdx.x & 7;
    int i = (blockIdx.x >> 3) * blockDim.x + threadIdx.x;
    int e0 = i * 4;
    if (e0 >= E) return;
    int d[4];
    int cnt;
    if (vec_ok && e0 + 3 < E) {
        int4 v = *(const int4*)(dst + e0);
        d[0] = v.x; d[1] = v.y; d[2] = v.z; d[3] = v.w; cnt = 4;
    } else {
        cnt = min(4, E - e0);
        for (int k = 0; k < cnt; ++k) d[k] = dst[e0 + k];
    }
    for (int k = 0; k < cnt; ++k) {
        int rr = min(7, (int)((float)d[k] * scale8));
        if (rr == r) slot[e0 + k] = atomicAdd(&deg[d[k]], 1);
    }
}

// scan pass 1 (+ float4-pack x: this grid is exactly N threads).
// Prefixes deg[g]+1 — the +1 is the implicit self-loop.
__global__ void scan_blocks(const int* __restrict__ deg,
                            int* __restrict__ off,
                            int* __restrict__ bsum,
                            const float* __restrict__ x,
                            float4* __restrict__ xq, int N) {
    __shared__ int sh[256];
    int t = threadIdx.x;
    int g = blockIdx.x * 256 + t;
    int v = (g < N) ? deg[g] + 1 : 0;
    if (g < N) xq[g] = make_float4(x[3 * g], x[3 * g + 1], x[3 * g + 2], 0.f);
    sh[t] = v;
    __syncthreads();
    for (int d = 1; d < 256; d <<= 1) {
        int xv = (t >= d) ? sh[t - d] : 0;
        __syncthreads();
        sh[t] += xv;
        __syncthreads();
    }
    if (g < N) off[g] = sh[t] - v;
    if (t == 255) bsum[blockIdx.x] = sh[255];
}

// scan pass 2+3 in ONE kernel: each block redundantly computes the prefix of
// bsum[0..bid), finalizes off, and plain-stores the self-loop into the
// node's LAST slot.  Last node writes off[N].
__global__ void scan_add(int* __restrict__ off, const int* __restrict__ bsum,
                         const int* __restrict__ deg,
                         int* __restrict__ csr_src, int N) {
    __shared__ int sh[256];
    int t = threadIdx.x, bid = blockIdx.x;
    int s = 0;
    for (int i = t; i < bid; i += 256) s += bsum[i];
    sh[t] = s;
    __syncthreads();
    for (int d = 128; d > 0; d >>= 1) {
        if (t < d) sh[t] += sh[t + d];
        __syncthreads();
    }
    int base = sh[0];
    int g = bid * 256 + t;
    if (g < N) {
        int o = off[g] + base;
        off[g] = o;
        int dg = deg[g];
        csr_src[o + dg] = g;
        if (g == N - 1) off[N] = o + dg + 1;
    }
}

// ---------------------------------------------------------------------------
// Atomic-free scatter MERGED with all weight prep (independent work; one
// dispatch by blockIdx range).
__device__ __forceinline__ void prep_blk(int b, int t, const float* W,
                                         const float* a_s, const float* a_d,
                                         unsigned short* Wb, float* ws,
                                         float* wd) {
    if (b < 64) {
        Wb[b * 256 + t] = (unsigned short)f2bf(W[(t >> 2) * HC + (t & 3) * CH + b]);
    } else {
        int idx = (b - 64) * 256 + t;      // 0..511
        int which = idx >= 256;
        int i = which ? idx - 256 : idx;   // i = k*4+h
        int k = i >> 2, h = i & 3;
        const float* av = (which ? a_d : a_s) + h * CH;
        const float* Wr = W + (size_t)k * HC + h * CH;
        float s = 0.f;
        for (int c = 0; c < CH; ++c) s += Wr[c] * av[c];
        (which ? wd : ws)[i] = s;
    }
}

__global__ void scatter_prep(const int* __restrict__ src,
                             const int* __restrict__ dst,
                             const int* __restrict__ slot, int E, int vec_ok,
                             const int* __restrict__ off,
                             int* __restrict__ csr_src, int CB,
                             const float* __restrict__ W1,
                             const float* __restrict__ a1s,
                             const float* __restrict__ a1d,
                             float* __restrict__ ws1, float* __restrict__ wd1,
                             const float* __restrict__ W2,
                             const float* __restrict__ a2s,
                             const float* __restrict__ a2d,
                             unsigned short* __restrict__ Wb2,
                             float* __restrict__ ws2, float* __restrict__ wd2,
                             const float* __restrict__ W3,
                             const float* __restrict__ a3s,
                             const float* __restrict__ a3d,
                             unsigned short* __restrict__ Wb3,
                             float* __restrict__ ws3, float* __restrict__ wd3) {
    int bid = blockIdx.x;
    int t = threadIdx.x;
    if (bid < CB) {
        int e0 = (bid * blockDim.x + t) * 4;
        if (e0 >= E) return;
        if (vec_ok && e0 + 3 < E) {
            int4 sv = *(const int4*)(src + e0);
            int4 dv = *(const int4*)(dst + e0);
            int4 pv = *(const int4*)(slot + e0);
            csr_src[off[dv.x] + pv.x] = sv.x;
            csr_src[off[dv.y] + pv.y] = sv.y;
            csr_src[off[dv.z] + pv.z] = sv.z;
            csr_src[off[dv.w] + pv.w] = sv.w;
        } else {
            int cnt = min(4, E - e0);
            for (int k = 0; k < cnt; ++k) {
                int e = e0 + k;
                csr_src[off[dst[e]] + slot[e]] = src[e];
            }
        }
        return;
    }
    int b = bid - CB;
    if (b < 66) {
        prep_blk(b, t, W2, a2s, a2d, Wb2, ws2, wd2);
    } else if (b < 132) {
        prep_blk(b - 66, t, W3, a3s, a3d, Wb3, ws3, wd3);
    } else {
        for (int idx = t; idx < 24; idx += blockDim.x) {
            int which = idx >= 12;
            int i = which ? idx - 12 : idx;
            int k = i >> 2, h = i & 3;
            const float* av = (which ? a1d : a1s) + h * CH;
            const float* Wr = W1 + (size_t)k * HC + h * CH;
            float s = 0.f;
            for (int c = 0; c < CH; ++c) s += Wr[c] * av[c];
            (which ? wd1 : ws1)[i] = s;
        }
    }
}

// ---------------------------------------------------------------------------
// Layer-1 aggregation: 8 LANES per node (6250 waves — 2x the round-11 MLP;
// ~2 independent 16B gathers per lane).  Writes compact zl.
__global__ void fused1_kernel(const int* __restrict__ off,
                              const int* __restrict__ csr_src,
                              const float4* __restrict__ xq,
                              const float* __restrict__ ws,   // ws1[12], k*4+h
                              const float* __restrict__ wd,   // wd1[12]
                              float4* __restrict__ zl, int N) {
    int t = blockIdx.x * blockDim.x + threadIdx.x;
    int n = t >> 3, j = t & 7;
    if (n >= N) return;
    float4 xn = xq[n];
    float ad0 = xn.x * wd[0] + xn.y * wd[4] + xn.z * wd[8];
    float ad1 = xn.x * wd[1] + xn.y * wd[5] + xn.z * wd[9];
    float ad2 = xn.x * wd[2] + xn.y * wd[6] + xn.z * wd[10];
    float ad3 = xn.x * wd[3] + xn.y * wd[7] + xn.z * wd[11];

    int o0 = off[n], o1 = off[n + 1];
    float z[12];
#pragma unroll
    for (int q = 0; q < 12; ++q) z[q] = 0.f;
    float l0 = 0.f, l1 = 0.f, l2 = 0.f, l3 = 0.f;

    for (int i = o0 + j; i < o1; i += 8) {
        int s = csr_src[i];
        float4 xv = xq[s];
        float e0 = __expf(lrelu(xv.x * ws[0] + xv.y * ws[4] + xv.z * ws[8]  + ad0));
        float e1 = __expf(lrelu(xv.x * ws[1] + xv.y * ws[5] + xv.z * ws[9]  + ad1));
        float e2 = __expf(lrelu(xv.x * ws[2] + xv.y * ws[6] + xv.z * ws[10] + ad2));
        float e3 = __expf(lrelu(xv.x * ws[3] + xv.y * ws[7] + xv.z * ws[11] + ad3));
        l0 += e0; l1 += e1; l2 += e2; l3 += e3;
        z[0] += e0 * xv.x; z[1]  += e0 * xv.y; z[2]  += e0 * xv.z;
        z[3] += e1 * xv.x; z[4]  += e1 * xv.y; z[5]  += e1 * xv.z;
        z[6] += e2 * xv.x; z[7]  += e2 * xv.y; z[8]  += e2 * xv.z;
        z[9] += e3 * xv.x; z[10] += e3 * xv.y; z[11] += e3 * xv.z;
    }
    // reduce across the 8 lanes of this node
#pragma unroll
    for (int m = 1; m < 8; m <<= 1) {
#pragma unroll
        for (int q = 0; q < 12; ++q) z[q] += __shfl_xor(z[q], m);
        l0 += __shfl_xor(l0, m);
        l1 += __shfl_xor(l1, m);
        l2 += __shfl_xor(l2, m);
        l3 += __shfl_xor(l3, m);
    }
    if (j == 0) {
        zl[(size_t)n * 4 + 0] = make_float4(z[0], z[1], z[2], z[3]);
        zl[(size_t)n * 4 + 1] = make_float4(z[4], z[5], z[6], z[7]);
        zl[(size_t)n * 4 + 2] = make_float4(z[8], z[9], z[10], z[11]);
        zl[(size_t)n * 4 + 3] = make_float4(l0, l1, l2, l3);
    }
}

// Layer-1 epilogue: wave per node (12.5k blocks — high occupancy, coalesced
// writes).  fp32 out + packed bf16 rows + FOLDED layer-2 logits.
__global__ void epi1_kernel(const float4* __restrict__ zl,
                            const float* __restrict__ W1,
                            const float* __restrict__ b1,
                            const float4* __restrict__ ws2_4,
                            const float4* __restrict__ wd2_4,
                            float4* __restrict__ asrc4,
                            float4* __restrict__ adst4,
                            float* __restrict__ out,
                            unsigned short* __restrict__ out_pack, int N) {
    int node = (blockIdx.x * blockDim.x + threadIdx.x) >> 6;
    int c = threadIdx.x & 63;
    if (node >= N) return;
    float4 z0 = zl[(size_t)node * 4 + 0];
    float4 z1 = zl[(size_t)node * 4 + 1];
    float4 z2 = zl[(size_t)node * 4 + 2];
    float4 l4 = zl[(size_t)node * 4 + 3];
    float i0 = 0.25f / l4.x, i1 = 0.25f / l4.y;
    float i2 = 0.25f / l4.z, i3 = 0.25f / l4.w;
    float acc =
        (z0.x * W1[0 * HC +   0 + c] + z0.y * W1[1 * HC +   0 + c] + z0.z * W1[2 * HC +   0 + c]) * i0 +
        (z0.w * W1[0 * HC +  64 + c] + z1.x * W1[1 * HC +  64 + c] + z1.y * W1[2 * HC +  64 + c]) * i1 +
        (z1.z * W1[0 * HC + 128 + c] + z1.w * W1[1 * HC + 128 + c] + z2.x * W1[2 * HC + 128 + c]) * i2 +
        (z2.y * W1[0 * HC + 192 + c] + z2.z * W1[1 * HC + 192 + c] + z2.w * W1[2 * HC + 192 + c]) * i3;
    float v = acc + b1[c];
    v = v > 0.f ? v : expm1f(v);
    out[(size_t)node * CH + c] = v;
    out_pack[(size_t)node * CH + c] = (unsigned short)f2bf(v);
    float4 wsv = ws2_4[c], wdv = wd2_4[c];
    float4 sacc = make_float4(v * wsv.x, v * wsv.y, v * wsv.z, v * wsv.w);
    float4 dacc = make_float4(v * wdv.x, v * wdv.y, v * wdv.z, v * wdv.w);
    sacc = wave_sum4(sacc);
    dacc = wave_sum4(dacc);
    if (c == 0) { asrc4[node] = sacc; adst4[node] = dacc; }
}

// ---------------------------------------------------------------------------
// Input-space aggregation (layers 2/3): wave per dst node, 4 edges/iter
// (quarter-wave per edge, 4 k-columns per lane via one 8B load).  4
// independent L2 row-loads in flight per iteration (was 2).  Final combine:
// xor16 + xor32 over z[16]+l[4].
__global__ void agg_kernel(const int* __restrict__ off,
                           const int* __restrict__ csr_src,
                           const unsigned short* __restrict__ xp,
                           const float4* __restrict__ asrc4,
                           const float4* __restrict__ adst4,
                           unsigned short* __restrict__ zb, int N) {
    __shared__ float4 exs[4][64];
    __shared__ unsigned int sss[4][64];
    int node = (blockIdx.x * blockDim.x + threadIdx.x) >> 6;
    int w = (threadIdx.x >> 6) & 3;
    int lane = threadIdx.x & 63;
    if (node >= N) return;
    int q = lane >> 4;             // quarter 0..3 = edge slot within group
    int lq = lane & 15;            // k-group: cols 4lq .. 4lq+3
    int o0 = off[node], o1 = off[node + 1];
    int deg = o1 - o0;
    float4 ad = adst4[node];

    float l0 = 0.f, l1 = 0.f, l2 = 0.f, l3 = 0.f;
    float z[16];
#pragma unroll
    for (int k = 0; k < 16; ++k) z[k] = 0.f;
    const char* xpb4 = (const char*)xp + lq * 8;

    for (int base = 0; base < deg; base += 64) {
        int i = base + lane;
        int s = 0;
        float4 ev = make_float4(-INFINITY, -INFINITY, -INFINITY, -INFINITY);
        if (i < deg) {
            s = csr_src[o0 + i];
            float4 as = asrc4[s];
            ev.x = lrelu(as.x + ad.x);
            ev.y = lrelu(as.y + ad.y);
            ev.z = lrelu(as.z + ad.z);
            ev.w = lrelu(as.w + ad.w);
        }
        float4 ex;
        ex.x = __expf(ev.x);   // inactive lanes: exp(-inf) = 0
        ex.y = __expf(ev.y);
        ex.z = __expf(ev.z);
        ex.w = __expf(ev.w);
        exs[w][lane] = ex;
        sss[w][lane] = (unsigned)s * 128u;   // byte offset of row s in xp

        int cnt = min(64, deg - base);
        // 4 edges per iteration; tail edges (e>=cnt) have exe==0.
        for (int e4 = 0; e4 < cnt; e4 += 4) {
            int e = e4 + q;
            unsigned soff = sss[w][e];       // 4-addr LDS read, distinct banks
            float4 exe = exs[w][e];
            l0 += exe.x; l1 += exe.y; l2 += exe.z; l3 += exe.w;
            uint2 xx = *(const uint2*)(xpb4 + soff);
            float xk0 = bf2f((unsigned short)(xx.x & 0xffffu));
            float xk1 = bf2f((unsigned short)(xx.x >> 16));
            float xk2 = bf2f((unsigned short)(xx.y & 0xffffu));
            float xk3 = bf2f((unsigned short)(xx.y >> 16));
            z[0]  += exe.x * xk0; z[1]  += exe.y * xk0;
            z[2]  += exe.z * xk0; z[3]  += exe.w * xk0;
            z[4]  += exe.x * xk1; z[5]  += exe.y * xk1;
            z[6]  += exe.z * xk1; z[7]  += exe.w * xk1;
            z[8]  += exe.x * xk2; z[9]  += exe.y * xk2;
            z[10] += exe.z * xk2; z[11] += exe.w * xk2;
            z[12] += exe.x * xk3; z[13] += exe.y * xk3;
            z[14] += exe.z * xk3; z[15] += exe.w * xk3;
        }
    }
    // combine the 4 quarter-chains (lanes with equal lq)
#pragma unroll
    for (int m = 16; m <= 32; m <<= 1) {
#pragma unroll
        for (int k = 0; k < 16; ++k) z[k] += __shfl_xor(z[k], m);
        l0 += __shfl_xor(l0, m);
        l1 += __shfl_xor(l1, m);
        l2 += __shfl_xor(l2, m);
        l3 += __shfl_xor(l3, m);
    }

    float s0 = 0.25f / l0, s1 = 0.25f / l1, s2 = 0.25f / l2, s3 = 0.25f / l3;
    if (q == 0) {
        // lane lq owns cols 4lq..4lq+3 -> bytes [32lq, 32lq+32) of row node
        uint4 a, b;
        a.x = f2bf(z[0]  * s0) | (f2bf(z[1]  * s1) << 16);
        a.y = f2bf(z[2]  * s2) | (f2bf(z[3]  * s3) << 16);
        a.z = f2bf(z[4]  * s0) | (f2bf(z[5]  * s1) << 16);
        a.w = f2bf(z[6]  * s2) | (f2bf(z[7]  * s3) << 16);
        b.x = f2bf(z[8]  * s0) | (f2bf(z[9]  * s1) << 16);
        b.y = f2bf(z[10] * s2) | (f2bf(z[11] * s3) << 16);
        b.z = f2bf(z[12] * s0) | (f2bf(z[13] * s1) << 16);
        b.w = f2bf(z[14] * s2) | (f2bf(z[15] * s3) << 16);
        char* p = (char*)zb + (size_t)node * 512 + lq * 32;
        *(uint4*)p = a;
        *(uint4*)(p + 16) = b;
    }
}

// ---------------------------------------------------------------------------
// MFMA post-aggregation GEMM (layers 2/3). A = zb (bf16 [n][j], j=k*4+h),
// B = Wb (bf16 [c][j]).  Layer-2 epilogue folds layer-3 logits; layer 3
// folds the final linear.
__global__ void gemm_mfma(const unsigned short* __restrict__ zb,
                          const unsigned short* __restrict__ Wb,
                          const float* __restrict__ bias,
                          const float* __restrict__ residual,
                          const float4* __restrict__ wsn4,
                          const float4* __restrict__ wdn4,
                          float4* __restrict__ asrc4,
                          float4* __restrict__ adst4,
                          const float* __restrict__ lin_w,
                          const float* __restrict__ lin_b,
                          float* __restrict__ out_f32,
                          unsigned short* __restrict__ out_pack,
                          float* __restrict__ out_final, int N) {
    int w = threadIdx.x >> 6;
    int lane = threadIdx.x & 63;
    int quad = lane >> 4, col = lane & 15;
    int nbase = blockIdx.x * 64 + w * 16;

    f32x4 zero4 = {0.f, 0.f, 0.f, 0.f};
    f32x4 acc[4];
#pragma unroll
    for (int t = 0; t < 4; ++t) acc[t] = zero4;

    const unsigned short* arow = zb + (size_t)(nbase + col) * HC + quad * 8;
#pragma unroll
    for (int q = 0; q < 8; ++q) {
        bf16x8 af = *(const bf16x8*)(arow + q * 32);
#pragma unroll
        for (int t = 0; t < 4; ++t) {
            const unsigned short* bp = Wb + (size_t)(t * 16 + col) * HC + q * 32 + quad * 8;
            bf16x8 bfrag = *(const bf16x8*)bp;
            acc[t] = __builtin_amdgcn_mfma_f32_16x16x32_bf16(af, bfrag, acc[t], 0, 0, 0);
        }
    }

    if (!out_final) {
        float vv[4][4];   // [t][r]
#pragma unroll
        for (int t = 0; t < 4; ++t) {
            int c = t * 16 + col;
            float bc = bias[c];
#pragma unroll
            for (int r = 0; r < 4; ++r) {
                int n = nbase + quad * 4 + r;
                float v = acc[t][r] + bc;
                v = v > 0.f ? v : expm1f(v);
                v += residual[(size_t)n * CH + c];
                vv[t][r] = v;
                if (n < N) {
                    out_f32[(size_t)n * CH + c] = v;
                    out_pack[(size_t)n * CH + c] = (unsigned short)f2bf(v);
                }
            }
        }
        float4 wsv[4], wdv[4];
#pragma unroll
        for (int t = 0; t < 4; ++t) { wsv[t] = wsn4[t * 16 + col]; wdv[t] = wdn4[t * 16 + col]; }
#pragma unroll
        for (int r = 0; r < 4; ++r) {
            int n = nbase + quad * 4 + r;
            float4 sa = make_float4(0.f, 0.f, 0.f, 0.f);
            float4 da = make_float4(0.f, 0.f, 0.f, 0.f);
#pragma unroll
            for (int t = 0; t < 4; ++t) {
                float v = vv[t][r];
                sa.x += v * wsv[t].x; sa.y += v * wsv[t].y;
                sa.z += v * wsv[t].z; sa.w += v * wsv[t].w;
                da.x += v * wdv[t].x; da.y += v * wdv[t].y;
                da.z += v * wdv[t].z; da.w += v * wdv[t].w;
            }
#pragma unroll
            for (int m = 8; m; m >>= 1) {
                sa.x += __shfl_xor(sa.x, m); sa.y += __shfl_xor(sa.y, m);
                sa.z += __shfl_xor(sa.z, m); sa.w += __shfl_xor(sa.w, m);
                da.x += __shfl_xor(da.x, m); da.y += __shfl_xor(da.y, m);
                da.z += __shfl_xor(da.z, m); da.w += __shfl_xor(da.w, m);
            }
            if (col == 0 && n < N) { asrc4[n] = sa; adst4[n] = da; }
        }
    } else {
        float lw[4], bb[4];
#pragma unroll
        for (int t = 0; t < 4; ++t) { lw[t] = lin_w[t * 16 + col]; bb[t] = bias[t * 16 + col]; }
#pragma unroll
        for (int r = 0; r < 4; ++r) {
            int n = nbase + quad * 4 + r;
            float ts = 0.f;
#pragma unroll
            for (int t = 0; t < 4; ++t) {
                float v = acc[t][r] + bb[t];
                v = v > 0.f ? v : expm1f(v);
                v += residual[(size_t)n * CH + (t * 16 + col)];
                ts += v * lw[t];
            }
            ts += __shfl_xor(ts, 1);
            ts += __shfl_xor(ts, 2);
            ts += __shfl_xor(ts, 4);
            ts += __shfl_xor(ts, 8);
            if (col == 0 && n < N) out_final[n] = ts + lin_b[0];
        }
    }
}

// ---------------------------------------------------------------------------
extern "C" void kernel_launch(void* const* d_in, const int* in_sizes, int n_in,
                              void* d_out, int out_size, void* d_ws, size_t ws_size,
                              hipStream_t stream) {
    const float* x      = (const float*)d_in[0];
    const int*   ei     = (const int*)  d_in[1];
    const float* W1     = (const float*)d_in[2];
    const float* a1s    = (const float*)d_in[3];
    const float* a1d    = (const float*)d_in[4];
    const float* b1     = (const float*)d_in[5];
    const float* W2     = (const float*)d_in[6];
    const float* a2s    = (const float*)d_in[7];
    const float* a2d    = (const float*)d_in[8];
    const float* b2     = (const float*)d_in[9];
    const float* W3     = (const float*)d_in[10];
    const float* a3s    = (const float*)d_in[11];
    const float* a3d    = (const float*)d_in[12];
    const float* b3     = (const float*)d_in[13];
    const float* lin_w  = (const float*)d_in[14];
    const float* lin_b  = (const float*)d_in[15];

    const int N = in_sizes[0] / 3;
    const int E = in_sizes[1] / 2;
    const int Et = E + N;
    const int* src = ei;
    const int* dst = ei + E;
    const float scale8 = 8.0f / (float)N;
    const int vec_ok = ((((size_t)src | (size_t)dst) & 15) == 0) ? 1 : 0;

    // ---- workspace layout (xq first for 16B alignment) ----
    float* xq_f   = (float*)d_ws;                         // N*4 (float4)
    unsigned short* zb  = (unsigned short*)(xq_f + (size_t)N * 4);  // N*256
    unsigned short* xpA = zb  + (size_t)N * HC;           // N*64
    unsigned short* xpB = xpA + (size_t)N * CH;           // N*64
    unsigned short* Wb2 = xpB + (size_t)N * CH;           // 16384
    unsigned short* Wb3 = Wb2 + 16384;                    // 16384
    float* bufA   = (float*)(Wb3 + 16384);                // N*64
    float* bufB   = bufA + (size_t)N * CH;                // N*64
    float* zl     = bufB + (size_t)N * CH;                // N*16
    float* asrc   = zl   + (size_t)N * 16;                // N*4
    float* adst   = asrc + (size_t)N * 4;                 // N*4
    float* ws1    = adst + (size_t)N * 4;                 // 16
    float* wd1    = ws1 + 16;                             // 16
    float* ws2    = wd1 + 16;                             // 256
    float* wd2    = ws2 + 256;                            // 256
    float* ws3    = wd2 + 256;                            // 256
    float* wd3    = ws3 + 256;                            // 256
    int* deg      = (int*)(wd3 + 256);                    // N
    int* off      = deg + N;                              // N+4
    int* bsum     = off + N + 4;                          // 1024
    int* slot     = bsum + 1024;                          // E
    int* csr_src  = slot + E;                             // Et

    const int B = 256;
    const int G = (N + 255) / 256;
    const int EB4 = (E + 3) / 4;                 // 4 edges per thread
    const int CB = (EB4 + B - 1) / B;

    // ---- CSR build + weight prep ----
    hipMemsetAsync(deg, 0, (size_t)N * sizeof(int), stream);
    count_kernel<<<CB * 8, B, 0, stream>>>(dst, E, vec_ok, scale8, deg, slot);
    scan_blocks<<<G, B, 0, stream>>>(deg, off, bsum, x, (float4*)xq_f, N);
    scan_add<<<G, B, 0, stream>>>(off, bsum, deg, csr_src, N);
    scatter_prep<<<CB + 133, B, 0, stream>>>(
        src, dst, slot, E, vec_ok, off, csr_src, CB,
        W1, a1s, a1d, ws1, wd1,
        W2, a2s, a2d, Wb2, ws2, wd2,
        W3, a3s, a3d, Wb3, ws3, wd3);

    int nwave_blocks = (N * 64 + B - 1) / B;   // wave per node
    int ngemm_blocks = (N + 63) / 64;          // 64 nodes per block

    // ---- Layer 1 (split: 8-lane agg + wave-node epilogue) ----
    fused1_kernel<<<(N * 8 + B - 1) / B, B, 0, stream>>>(
        off, csr_src, (const float4*)xq_f, ws1, wd1, (float4*)zl, N);
    epi1_kernel<<<nwave_blocks, B, 0, stream>>>(
        (const float4*)zl, W1, b1, (const float4*)ws2, (const float4*)wd2,
        (float4*)asrc, (float4*)adst, bufA, xpA, N);

    // ---- Layer 2 (gemm epilogue folds layer-3 logits) ----
    agg_kernel<<<nwave_blocks, B, 0, stream>>>(
        off, csr_src, xpA, (const float4*)asrc, (const float4*)adst,
        zb, N);
    gemm_mfma<<<ngemm_blocks, B, 0, stream>>>(
        zb, Wb2, b2, bufA, (const float4*)ws3, (const float4*)wd3,
        (float4*)asrc, (float4*)adst,
        nullptr, nullptr, bufB, xpB, nullptr, N);

    // ---- Layer 3 (+ fused final linear) ----
    agg_kernel<<<nwave_blocks, B, 0, stream>>>(
        off, csr_src, xpB, (const float4*)asrc, (const float4*)adst,
        zb, N);
    gemm_mfma<<<ngemm_blocks, B, 0, stream>>>(
        zb, Wb3, b3, bufB, nullptr, nullptr, nullptr, nullptr,
        lin_w, lin_b, nullptr, nullptr, (float*)d_out, N);
}

// Round 13
// 303.527 us; speedup vs baseline: 1.0339x; 1.0339x over previous
//
#include <hip/hip_runtime.h>
#include <math.h>

#define HEADS 4
#define CH 64
#define HC 256   // HEADS*CH

typedef __attribute__((ext_vector_type(8))) short bf16x8;
typedef __attribute__((ext_vector_type(4))) float f32x4;

__device__ __forceinline__ float lrelu(float v) { return v > 0.f ? v : 0.2f * v; }

// fp32 -> bf16 bits, round-to-nearest-even
__device__ __forceinline__ unsigned int f2bf(float f) {
    unsigned int u = __float_as_uint(f);
    u += 0x7fffu + ((u >> 16) & 1u);
    return u >> 16;
}
__device__ __forceinline__ float bf2f(unsigned short u) {
    return __uint_as_float(((unsigned int)u) << 16);
}

__device__ __forceinline__ float4 wave_sum4(float4 v) {
#pragma unroll
    for (int m = 32; m; m >>= 1) {
        v.x += __shfl_xor(v.x, m);
        v.y += __shfl_xor(v.y, m);
        v.z += __shfl_xor(v.z, m);
        v.w += __shfl_xor(v.w, m);
    }
    return v;
}

// ---------------------------------------------------------------------------
// CSR build. count is XCD-affine and RECORDS each edge's slot (atomicAdd
// return) so scatter needs no atomics and no replication.
__global__ void count_kernel(const int* __restrict__ dst, int E, int vec_ok,
                             float scale8, int* __restrict__ deg,
                             int* __restrict__ slot) {
    int r = blockIdx.x & 7;
    int i = (blockIdx.x >> 3) * blockDim.x + threadIdx.x;
    int e0 = i * 4;
    if (e0 >= E) return;
    int d[4];
    int cnt;
    if (vec_ok && e0 + 3 < E) {
        int4 v = *(const int4*)(dst + e0);
        d[0] = v.x; d[1] = v.y; d[2] = v.z; d[3] = v.w; cnt = 4;
    } else {
        cnt = min(4, E - e0);
        for (int k = 0; k < cnt; ++k) d[k] = dst[e0 + k];
    }
    for (int k = 0; k < cnt; ++k) {
        int rr = min(7, (int)((float)d[k] * scale8));
        if (rr == r) slot[e0 + k] = atomicAdd(&deg[d[k]], 1);
    }
}

// scan pass 1 (+ float4-pack x: this grid is exactly N threads).
// Prefixes deg[g]+1 — the +1 is the implicit self-loop.
__global__ void scan_blocks(const int* __restrict__ deg,
                            int* __restrict__ off,
                            int* __restrict__ bsum,
                            const float* __restrict__ x,
                            float4* __restrict__ xq, int N) {
    __shared__ int sh[256];
    int t = threadIdx.x;
    int g = blockIdx.x * 256 + t;
    int v = (g < N) ? deg[g] + 1 : 0;
    if (g < N) xq[g] = make_float4(x[3 * g], x[3 * g + 1], x[3 * g + 2], 0.f);
    sh[t] = v;
    __syncthreads();
    for (int d = 1; d < 256; d <<= 1) {
        int xv = (t >= d) ? sh[t - d] : 0;
        __syncthreads();
        sh[t] += xv;
        __syncthreads();
    }
    if (g < N) off[g] = sh[t] - v;
    if (t == 255) bsum[blockIdx.x] = sh[255];
}

// scan pass 2+3 in ONE kernel: each block redundantly computes the prefix of
// bsum[0..bid), finalizes off, and plain-stores the self-loop into the
// node's LAST slot.  Last node writes off[N].
__global__ void scan_add(int* __restrict__ off, const int* __restrict__ bsum,
                         const int* __restrict__ deg,
                         int* __restrict__ csr_src, int N) {
    __shared__ int sh[256];
    int t = threadIdx.x, bid = blockIdx.x;
    int s = 0;
    for (int i = t; i < bid; i += 256) s += bsum[i];
    sh[t] = s;
    __syncthreads();
    for (int d = 128; d > 0; d >>= 1) {
        if (t < d) sh[t] += sh[t + d];
        __syncthreads();
    }
    int base = sh[0];
    int g = bid * 256 + t;
    if (g < N) {
        int o = off[g] + base;
        off[g] = o;
        int dg = deg[g];
        csr_src[o + dg] = g;
        if (g == N - 1) off[N] = o + dg + 1;
    }
}

// ---------------------------------------------------------------------------
// Atomic-free scatter MERGED with all weight prep (independent work; one
// dispatch by blockIdx range).
__device__ __forceinline__ void prep_blk(int b, int t, const float* W,
                                         const float* a_s, const float* a_d,
                                         unsigned short* Wb, float* ws,
                                         float* wd) {
    if (b < 64) {
        Wb[b * 256 + t] = (unsigned short)f2bf(W[(t >> 2) * HC + (t & 3) * CH + b]);
    } else {
        int idx = (b - 64) * 256 + t;      // 0..511
        int which = idx >= 256;
        int i = which ? idx - 256 : idx;   // i = k*4+h
        int k = i >> 2, h = i & 3;
        const float* av = (which ? a_d : a_s) + h * CH;
        const float* Wr = W + (size_t)k * HC + h * CH;
        float s = 0.f;
        for (int c = 0; c < CH; ++c) s += Wr[c] * av[c];
        (which ? wd : ws)[i] = s;
    }
}

__global__ void scatter_prep(const int* __restrict__ src,
                             const int* __restrict__ dst,
                             const int* __restrict__ slot, int E, int vec_ok,
                             const int* __restrict__ off,
                             int* __restrict__ csr_src, int CB,
                             const float* __restrict__ W1,
                             const float* __restrict__ a1s,
                             const float* __restrict__ a1d,
                             float* __restrict__ ws1, float* __restrict__ wd1,
                             const float* __restrict__ W2,
                             const float* __restrict__ a2s,
                             const float* __restrict__ a2d,
                             unsigned short* __restrict__ Wb2,
                             float* __restrict__ ws2, float* __restrict__ wd2,
                             const float* __restrict__ W3,
                             const float* __restrict__ a3s,
                             const float* __restrict__ a3d,
                             unsigned short* __restrict__ Wb3,
                             float* __restrict__ ws3, float* __restrict__ wd3) {
    int bid = blockIdx.x;
    int t = threadIdx.x;
    if (bid < CB) {
        int e0 = (bid * blockDim.x + t) * 4;
        if (e0 >= E) return;
        if (vec_ok && e0 + 3 < E) {
            int4 sv = *(const int4*)(src + e0);
            int4 dv = *(const int4*)(dst + e0);
            int4 pv = *(const int4*)(slot + e0);
            csr_src[off[dv.x] + pv.x] = sv.x;
            csr_src[off[dv.y] + pv.y] = sv.y;
            csr_src[off[dv.z] + pv.z] = sv.z;
            csr_src[off[dv.w] + pv.w] = sv.w;
        } else {
            int cnt = min(4, E - e0);
            for (int k = 0; k < cnt; ++k) {
                int e = e0 + k;
                csr_src[off[dst[e]] + slot[e]] = src[e];
            }
        }
        return;
    }
    int b = bid - CB;
    if (b < 66) {
        prep_blk(b, t, W2, a2s, a2d, Wb2, ws2, wd2);
    } else if (b < 132) {
        prep_blk(b - 66, t, W3, a3s, a3d, Wb3, ws3, wd3);
    } else {
        for (int idx = t; idx < 24; idx += blockDim.x) {
            int which = idx >= 12;
            int i = which ? idx - 12 : idx;
            int k = i >> 2, h = i & 3;
            const float* av = (which ? a1d : a1s) + h * CH;
            const float* Wr = W1 + (size_t)k * HC + h * CH;
            float s = 0.f;
            for (int c = 0; c < CH; ++c) s += Wr[c] * av[c];
            (which ? wd1 : ws1)[i] = s;
        }
    }
}

// ---------------------------------------------------------------------------
// Layer-1 aggregation: 4 LANES per node (3125 waves; float4 x loads; logits
// inline).  Writes compact zl.  (Bracketed: 1-lane and 8-lane both slower.)
__global__ void fused1_kernel(const int* __restrict__ off,
                              const int* __restrict__ csr_src,
                              const float4* __restrict__ xq,
                              const float* __restrict__ ws,   // ws1[12], k*4+h
                              const float* __restrict__ wd,   // wd1[12]
                              float4* __restrict__ zl, int N) {
    int t = blockIdx.x * blockDim.x + threadIdx.x;
    int n = t >> 2, j = t & 3;
    if (n >= N) return;
    float4 xn = xq[n];
    float ad0 = xn.x * wd[0] + xn.y * wd[4] + xn.z * wd[8];
    float ad1 = xn.x * wd[1] + xn.y * wd[5] + xn.z * wd[9];
    float ad2 = xn.x * wd[2] + xn.y * wd[6] + xn.z * wd[10];
    float ad3 = xn.x * wd[3] + xn.y * wd[7] + xn.z * wd[11];

    int o0 = off[n], o1 = off[n + 1];
    float z[12];
#pragma unroll
    for (int q = 0; q < 12; ++q) z[q] = 0.f;
    float l0 = 0.f, l1 = 0.f, l2 = 0.f, l3 = 0.f;

    for (int i = o0 + j; i < o1; i += 4) {
        int s = csr_src[i];
        float4 xv = xq[s];
        float e0 = __expf(lrelu(xv.x * ws[0] + xv.y * ws[4] + xv.z * ws[8]  + ad0));
        float e1 = __expf(lrelu(xv.x * ws[1] + xv.y * ws[5] + xv.z * ws[9]  + ad1));
        float e2 = __expf(lrelu(xv.x * ws[2] + xv.y * ws[6] + xv.z * ws[10] + ad2));
        float e3 = __expf(lrelu(xv.x * ws[3] + xv.y * ws[7] + xv.z * ws[11] + ad3));
        l0 += e0; l1 += e1; l2 += e2; l3 += e3;
        z[0] += e0 * xv.x; z[1]  += e0 * xv.y; z[2]  += e0 * xv.z;
        z[3] += e1 * xv.x; z[4]  += e1 * xv.y; z[5]  += e1 * xv.z;
        z[6] += e2 * xv.x; z[7]  += e2 * xv.y; z[8]  += e2 * xv.z;
        z[9] += e3 * xv.x; z[10] += e3 * xv.y; z[11] += e3 * xv.z;
    }
    // reduce across the 4 lanes of this node
#pragma unroll
    for (int m = 1; m < 4; m <<= 1) {
#pragma unroll
        for (int q = 0; q < 12; ++q) z[q] += __shfl_xor(z[q], m);
        l0 += __shfl_xor(l0, m);
        l1 += __shfl_xor(l1, m);
        l2 += __shfl_xor(l2, m);
        l3 += __shfl_xor(l3, m);
    }
    if (j == 0) {
        zl[(size_t)n * 4 + 0] = make_float4(z[0], z[1], z[2], z[3]);
        zl[(size_t)n * 4 + 1] = make_float4(z[4], z[5], z[6], z[7]);
        zl[(size_t)n * 4 + 2] = make_float4(z[8], z[9], z[10], z[11]);
        zl[(size_t)n * 4 + 3] = make_float4(l0, l1, l2, l3);
    }
}

// Layer-1 epilogue: wave per node (12.5k blocks — high occupancy, coalesced
// writes).  fp32 out + packed bf16 rows + FOLDED layer-2 logits.
__global__ void epi1_kernel(const float4* __restrict__ zl,
                            const float* __restrict__ W1,
                            const float* __restrict__ b1,
                            const float4* __restrict__ ws2_4,
                            const float4* __restrict__ wd2_4,
                            float4* __restrict__ asrc4,
                            float4* __restrict__ adst4,
                            float* __restrict__ out,
                            unsigned short* __restrict__ out_pack, int N) {
    int node = (blockIdx.x * blockDim.x + threadIdx.x) >> 6;
    int c = threadIdx.x & 63;
    if (node >= N) return;
    float4 z0 = zl[(size_t)node * 4 + 0];
    float4 z1 = zl[(size_t)node * 4 + 1];
    float4 z2 = zl[(size_t)node * 4 + 2];
    float4 l4 = zl[(size_t)node * 4 + 3];
    float i0 = 0.25f / l4.x, i1 = 0.25f / l4.y;
    float i2 = 0.25f / l4.z, i3 = 0.25f / l4.w;
    float acc =
        (z0.x * W1[0 * HC +   0 + c] + z0.y * W1[1 * HC +   0 + c] + z0.z * W1[2 * HC +   0 + c]) * i0 +
        (z0.w * W1[0 * HC +  64 + c] + z1.x * W1[1 * HC +  64 + c] + z1.y * W1[2 * HC +  64 + c]) * i1 +
        (z1.z * W1[0 * HC + 128 + c] + z1.w * W1[1 * HC + 128 + c] + z2.x * W1[2 * HC + 128 + c]) * i2 +
        (z2.y * W1[0 * HC + 192 + c] + z2.z * W1[1 * HC + 192 + c] + z2.w * W1[2 * HC + 192 + c]) * i3;
    float v = acc + b1[c];
    v = v > 0.f ? v : expm1f(v);
    out[(size_t)node * CH + c] = v;
    out_pack[(size_t)node * CH + c] = (unsigned short)f2bf(v);
    float4 wsv = ws2_4[c], wdv = wd2_4[c];
    float4 sacc = make_float4(v * wsv.x, v * wsv.y, v * wsv.z, v * wsv.w);
    float4 dacc = make_float4(v * wdv.x, v * wdv.y, v * wdv.z, v * wdv.w);
    sacc = wave_sum4(sacc);
    dacc = wave_sum4(dacc);
    if (c == 0) { asrc4[node] = sacc; adst4[node] = dacc; }
}

// ---------------------------------------------------------------------------
// Input-space aggregation (layers 2/3): wave per dst node, 2 edges/iter
// (half-wave per edge, 2 k-columns per lane).  l accumulated in phase 2 from
// the LDS-broadcast exe.  (Bracketed: 1-edge and 4-edge both slower.)
__global__ void agg_kernel(const int* __restrict__ off,
                           const int* __restrict__ csr_src,
                           const unsigned short* __restrict__ xp,
                           const float4* __restrict__ asrc4,
                           const float4* __restrict__ adst4,
                           unsigned short* __restrict__ zb, int N) {
    __shared__ float4 exs[4][64];
    __shared__ unsigned int sss[4][64];
    int node = (blockIdx.x * blockDim.x + threadIdx.x) >> 6;
    int w = (threadIdx.x >> 6) & 3;
    int lane = threadIdx.x & 63;
    if (node >= N) return;
    int half = lane >> 5;          // which edge of the pair
    int lk = lane & 31;            // k-pair index: k = 2*lk, 2*lk+1
    int o0 = off[node], o1 = off[node + 1];
    int deg = o1 - o0;
    float4 ad = adst4[node];

    float l0 = 0.f, l1 = 0.f, l2 = 0.f, l3 = 0.f;
    float z[8];
#pragma unroll
    for (int q = 0; q < 8; ++q) z[q] = 0.f;
    const char* xpb2 = (const char*)xp + lk * 4;

    for (int base = 0; base < deg; base += 64) {
        int i = base + lane;
        int s = 0;
        float4 ev = make_float4(-INFINITY, -INFINITY, -INFINITY, -INFINITY);
        if (i < deg) {
            s = csr_src[o0 + i];
            float4 as = asrc4[s];
            ev.x = lrelu(as.x + ad.x);
            ev.y = lrelu(as.y + ad.y);
            ev.z = lrelu(as.z + ad.z);
            ev.w = lrelu(as.w + ad.w);
        }
        float4 ex;
        ex.x = __expf(ev.x);   // inactive lanes: exp(-inf) = 0
        ex.y = __expf(ev.y);
        ex.z = __expf(ev.z);
        ex.w = __expf(ev.w);
        exs[w][lane] = ex;
        sss[w][lane] = (unsigned)s * 128u;   // byte offset of row s in xp

        int cnt = min(64, deg - base);
        // 2 edges per iteration; tail edge (e==cnt) has exe==0.
#pragma unroll 2
        for (int e2 = 0; e2 < cnt; e2 += 2) {
            int e = e2 + half;
            unsigned soff = sss[w][e];       // 2-addr LDS broadcast (free)
            float4 exe = exs[w][e];
            l0 += exe.x; l1 += exe.y; l2 += exe.z; l3 += exe.w;
            unsigned xx = *(const unsigned*)(xpb2 + soff);
            float xk0 = bf2f((unsigned short)(xx & 0xffffu));
            float xk1 = bf2f((unsigned short)(xx >> 16));
            z[0] += exe.x * xk0; z[1] += exe.y * xk0;
            z[2] += exe.z * xk0; z[3] += exe.w * xk0;
            z[4] += exe.x * xk1; z[5] += exe.y * xk1;
            z[6] += exe.z * xk1; z[7] += exe.w * xk1;
        }
    }
    // combine even/odd edge chains across the two halves
#pragma unroll
    for (int q = 0; q < 8; ++q) z[q] += __shfl_xor(z[q], 32);
    l0 += __shfl_xor(l0, 32);
    l1 += __shfl_xor(l1, 32);
    l2 += __shfl_xor(l2, 32);
    l3 += __shfl_xor(l3, 32);

    float s0 = 0.25f / l0, s1 = 0.25f / l1, s2 = 0.25f / l2, s3 = 0.25f / l3;
    if (half == 0) {
        uint4 zo;   // zb[node][j], j=k*4+h: k0 -> j=8lk.., k1 -> j=8lk+4..
        zo.x = f2bf(z[0] * s0) | (f2bf(z[1] * s1) << 16);
        zo.y = f2bf(z[2] * s2) | (f2bf(z[3] * s3) << 16);
        zo.z = f2bf(z[4] * s0) | (f2bf(z[5] * s1) << 16);
        zo.w = f2bf(z[6] * s2) | (f2bf(z[7] * s3) << 16);
        *(uint4*)((char*)zb + (size_t)node * 512 + lk * 16) = zo;
    }
}

// ---------------------------------------------------------------------------
// MFMA post-aggregation GEMM (layers 2/3). A = zb (bf16 [n][j], j=k*4+h),
// B = Wb (bf16 [c][j]).  Layer-2 epilogue folds layer-3 logits; layer 3
// folds the final linear.
__global__ void gemm_mfma(const unsigned short* __restrict__ zb,
                          const unsigned short* __restrict__ Wb,
                          const float* __restrict__ bias,
                          const float* __restrict__ residual,
                          const float4* __restrict__ wsn4,
                          const float4* __restrict__ wdn4,
                          float4* __restrict__ asrc4,
                          float4* __restrict__ adst4,
                          const float* __restrict__ lin_w,
                          const float* __restrict__ lin_b,
                          float* __restrict__ out_f32,
                          unsigned short* __restrict__ out_pack,
                          float* __restrict__ out_final, int N) {
    int w = threadIdx.x >> 6;
    int lane = threadIdx.x & 63;
    int quad = lane >> 4, col = lane & 15;
    int nbase = blockIdx.x * 64 + w * 16;

    f32x4 zero4 = {0.f, 0.f, 0.f, 0.f};
    f32x4 acc[4];
#pragma unroll
    for (int t = 0; t < 4; ++t) acc[t] = zero4;

    const unsigned short* arow = zb + (size_t)(nbase + col) * HC + quad * 8;
#pragma unroll
    for (int q = 0; q < 8; ++q) {
        bf16x8 af = *(const bf16x8*)(arow + q * 32);
#pragma unroll
        for (int t = 0; t < 4; ++t) {
            const unsigned short* bp = Wb + (size_t)(t * 16 + col) * HC + q * 32 + quad * 8;
            bf16x8 bfrag = *(const bf16x8*)bp;
            acc[t] = __builtin_amdgcn_mfma_f32_16x16x32_bf16(af, bfrag, acc[t], 0, 0, 0);
        }
    }

    if (!out_final) {
        float vv[4][4];   // [t][r]
#pragma unroll
        for (int t = 0; t < 4; ++t) {
            int c = t * 16 + col;
            float bc = bias[c];
#pragma unroll
            for (int r = 0; r < 4; ++r) {
                int n = nbase + quad * 4 + r;
                float v = acc[t][r] + bc;
                v = v > 0.f ? v : expm1f(v);
                v += residual[(size_t)n * CH + c];
                vv[t][r] = v;
                if (n < N) {
                    out_f32[(size_t)n * CH + c] = v;
                    out_pack[(size_t)n * CH + c] = (unsigned short)f2bf(v);
                }
            }
        }
        float4 wsv[4], wdv[4];
#pragma unroll
        for (int t = 0; t < 4; ++t) { wsv[t] = wsn4[t * 16 + col]; wdv[t] = wdn4[t * 16 + col]; }
#pragma unroll
        for (int r = 0; r < 4; ++r) {
            int n = nbase + quad * 4 + r;
            float4 sa = make_float4(0.f, 0.f, 0.f, 0.f);
            float4 da = make_float4(0.f, 0.f, 0.f, 0.f);
#pragma unroll
            for (int t = 0; t < 4; ++t) {
                float v = vv[t][r];
                sa.x += v * wsv[t].x; sa.y += v * wsv[t].y;
                sa.z += v * wsv[t].z; sa.w += v * wsv[t].w;
                da.x += v * wdv[t].x; da.y += v * wdv[t].y;
                da.z += v * wdv[t].z; da.w += v * wdv[t].w;
            }
#pragma unroll
            for (int m = 8; m; m >>= 1) {
                sa.x += __shfl_xor(sa.x, m); sa.y += __shfl_xor(sa.y, m);
                sa.z += __shfl_xor(sa.z, m); sa.w += __shfl_xor(sa.w, m);
                da.x += __shfl_xor(da.x, m); da.y += __shfl_xor(da.y, m);
                da.z += __shfl_xor(da.z, m); da.w += __shfl_xor(da.w, m);
            }
            if (col == 0 && n < N) { asrc4[n] = sa; adst4[n] = da; }
        }
    } else {
        float lw[4], bb[4];
#pragma unroll
        for (int t = 0; t < 4; ++t) { lw[t] = lin_w[t * 16 + col]; bb[t] = bias[t * 16 + col]; }
#pragma unroll
        for (int r = 0; r < 4; ++r) {
            int n = nbase + quad * 4 + r;
            float ts = 0.f;
#pragma unroll
            for (int t = 0; t < 4; ++t) {
                float v = acc[t][r] + bb[t];
                v = v > 0.f ? v : expm1f(v);
                v += residual[(size_t)n * CH + (t * 16 + col)];
                ts += v * lw[t];
            }
            ts += __shfl_xor(ts, 1);
            ts += __shfl_xor(ts, 2);
            ts += __shfl_xor(ts, 4);
            ts += __shfl_xor(ts, 8);
            if (col == 0 && n < N) out_final[n] = ts + lin_b[0];
        }
    }
}

// ---------------------------------------------------------------------------
extern "C" void kernel_launch(void* const* d_in, const int* in_sizes, int n_in,
                              void* d_out, int out_size, void* d_ws, size_t ws_size,
                              hipStream_t stream) {
    const float* x      = (const float*)d_in[0];
    const int*   ei     = (const int*)  d_in[1];
    const float* W1     = (const float*)d_in[2];
    const float* a1s    = (const float*)d_in[3];
    const float* a1d    = (const float*)d_in[4];
    const float* b1     = (const float*)d_in[5];
    const float* W2     = (const float*)d_in[6];
    const float* a2s    = (const float*)d_in[7];
    const float* a2d    = (const float*)d_in[8];
    const float* b2     = (const float*)d_in[9];
    const float* W3     = (const float*)d_in[10];
    const float* a3s    = (const float*)d_in[11];
    const float* a3d    = (const float*)d_in[12];
    const float* b3     = (const float*)d_in[13];
    const float* lin_w  = (const float*)d_in[14];
    const float* lin_b  = (const float*)d_in[15];

    const int N = in_sizes[0] / 3;
    const int E = in_sizes[1] / 2;
    const int Et = E + N;
    const int* src = ei;
    const int* dst = ei + E;
    const float scale8 = 8.0f / (float)N;
    const int vec_ok = ((((size_t)src | (size_t)dst) & 15) == 0) ? 1 : 0;

    // ---- workspace layout (xq first for 16B alignment) ----
    float* xq_f   = (float*)d_ws;                         // N*4 (float4)
    unsigned short* zb  = (unsigned short*)(xq_f + (size_t)N * 4);  // N*256
    unsigned short* xpA = zb  + (size_t)N * HC;           // N*64
    unsigned short* xpB = xpA + (size_t)N * CH;           // N*64
    unsigned short* Wb2 = xpB + (size_t)N * CH;           // 16384
    unsigned short* Wb3 = Wb2 + 16384;                    // 16384
    float* bufA   = (float*)(Wb3 + 16384);                // N*64
    float* bufB   = bufA + (size_t)N * CH;                // N*64
    float* zl     = bufB + (size_t)N * CH;                // N*16
    float* asrc   = zl   + (size_t)N * 16;                // N*4
    float* adst   = asrc + (size_t)N * 4;                 // N*4
    float* ws1    = adst + (size_t)N * 4;                 // 16
    float* wd1    = ws1 + 16;                             // 16
    float* ws2    = wd1 + 16;                             // 256
    float* wd2    = ws2 + 256;                            // 256
    float* ws3    = wd2 + 256;                            // 256
    float* wd3    = ws3 + 256;                            // 256
    int* deg      = (int*)(wd3 + 256);                    // N
    int* off      = deg + N;                              // N+4
    int* bsum     = off + N + 4;                          // 1024
    int* slot     = bsum + 1024;                          // E
    int* csr_src  = slot + E;                             // Et

    const int B = 256;
    const int G = (N + 255) / 256;
    const int EB4 = (E + 3) / 4;                 // 4 edges per thread
    const int CB = (EB4 + B - 1) / B;

    // ---- CSR build + weight prep ----
    hipMemsetAsync(deg, 0, (size_t)N * sizeof(int), stream);
    count_kernel<<<CB * 8, B, 0, stream>>>(dst, E, vec_ok, scale8, deg, slot);
    scan_blocks<<<G, B, 0, stream>>>(deg, off, bsum, x, (float4*)xq_f, N);
    scan_add<<<G, B, 0, stream>>>(off, bsum, deg, csr_src, N);
    scatter_prep<<<CB + 133, B, 0, stream>>>(
        src, dst, slot, E, vec_ok, off, csr_src, CB,
        W1, a1s, a1d, ws1, wd1,
        W2, a2s, a2d, Wb2, ws2, wd2,
        W3, a3s, a3d, Wb3, ws3, wd3);

    int nwave_blocks = (N * 64 + B - 1) / B;   // wave per node
    int ngemm_blocks = (N + 63) / 64;          // 64 nodes per block

    // ---- Layer 1 (split: 4-lane agg + wave-node epilogue — measured best) ----
    fused1_kernel<<<(N * 4 + B - 1) / B, B, 0, stream>>>(
        off, csr_src, (const float4*)xq_f, ws1, wd1, (float4*)zl, N);
    epi1_kernel<<<nwave_blocks, B, 0, stream>>>(
        (const float4*)zl, W1, b1, (const float4*)ws2, (const float4*)wd2,
        (float4*)asrc, (float4*)adst, bufA, xpA, N);

    // ---- Layer 2 (gemm epilogue folds layer-3 logits) ----
    agg_kernel<<<nwave_blocks, B, 0, stream>>>(
        off, csr_src, xpA, (const float4*)asrc, (const float4*)adst,
        zb, N);
    gemm_mfma<<<ngemm_blocks, B, 0, stream>>>(
        zb, Wb2, b2, bufA, (const float4*)ws3, (const float4*)wd3,
        (float4*)asrc, (float4*)adst,
        nullptr, nullptr, bufB, xpB, nullptr, N);

    // ---- Layer 3 (+ fused final linear) ----
    agg_kernel<<<nwave_blocks, B, 0, stream>>>(
        off, csr_src, xpB, (const float4*)asrc, (const float4*)adst,
        zb, N);
    gemm_mfma<<<ngemm_blocks, B, 0, stream>>>(
        zb, Wb3, b3, bufB, nullptr, nullptr, nullptr, nullptr,
        lin_w, lin_b, nullptr, nullptr, (float*)d_out, N);
}